// Round 1
// baseline (8785.155 us; speedup 1.0000x reference)
//
#include <hip/hip_runtime.h>
#include <hip/hip_bf16.h>
#include <math.h>

// Shapes (fixed by the problem)
#define Bsz 64
#define Pp  196
#define ENC 2048
#define Ee  512
#define Hh  512
#define Vv  10000
#define Tt  20
#define H4  2048   // 4*H

__device__ __forceinline__ float sigmoidf_(float x) { return 1.0f / (1.0f + expf(-x)); }

// v_enc[e] = sum_a W_full[a] * W_enc_att[a*ENC + e]
__global__ __launch_bounds__(256) void k_venc(const float* __restrict__ W_full,
                                              const float* __restrict__ W_enc,
                                              float* __restrict__ v_enc) {
    int e = blockIdx.x * 256 + threadIdx.x;
    if (e >= ENC) return;
    float s = 0.f;
    for (int a = 0; a < 512; ++a) s += W_full[a] * W_enc[a * ENC + e];
    v_enc[e] = s;
}

// One block per batch b: scores -> softmax -> alphas out, context, avg
__global__ __launch_bounds__(256) void k_attn(const float* __restrict__ img,
                                              const float* __restrict__ v_enc,
                                              float* __restrict__ context,
                                              float* __restrict__ avg,
                                              float* __restrict__ alphas_out) {
    int b = blockIdx.x;
    int tid = threadIdx.x;
    __shared__ float sv[ENC];
    __shared__ float sc[256];
    __shared__ float red[256];

    for (int e = tid; e < ENC; e += 256) sv[e] = v_enc[e];
    __syncthreads();

    const float* ib = img + (size_t)b * Pp * ENC;
    int wave = tid >> 6, lane = tid & 63;
    for (int p = wave; p < Pp; p += 4) {
        const float* row = ib + (size_t)p * ENC;
        float s = 0.f;
        for (int k = lane; k < ENC; k += 64) s += row[k] * sv[k];
        for (int off = 32; off > 0; off >>= 1) s += __shfl_down(s, off);
        if (lane == 0) sc[p] = s;
    }
    __syncthreads();

    // softmax over 196
    float v = (tid < Pp) ? sc[tid] : -INFINITY;
    red[tid] = v; __syncthreads();
    for (int off = 128; off > 0; off >>= 1) {
        if (tid < off) red[tid] = fmaxf(red[tid], red[tid + off]);
        __syncthreads();
    }
    float mx = red[0]; __syncthreads();
    float ex = (tid < Pp) ? expf(sc[tid] - mx) : 0.f;
    red[tid] = ex; __syncthreads();
    for (int off = 128; off > 0; off >>= 1) {
        if (tid < off) red[tid] += red[tid + off];
        __syncthreads();
    }
    float inv = 1.f / red[0];
    __syncthreads();
    if (tid < Pp) sc[tid] = ex * inv;   // alpha
    __syncthreads();

    // alphas output: [b][t][p], identical for every t
    for (int i = tid; i < Tt * Pp; i += 256) {
        int p = i % Pp;
        alphas_out[(size_t)b * Tt * Pp + i] = sc[p];
    }

    // context + avg
    for (int e = tid; e < ENC; e += 256) {
        float cs = 0.f, as = 0.f;
        for (int p = 0; p < Pp; ++p) {
            float val = ib[(size_t)p * ENC + e];
            cs += sc[p] * val;
            as += val;
        }
        context[(size_t)b * ENC + e] = cs;
        avg[(size_t)b * ENC + e] = as * (1.0f / 196.0f);
    }
}

// emb_all[(t*B+b)*E + e] = embedding[captions[b*T+t]*E + e]
__global__ __launch_bounds__(256) void k_gather(const int* __restrict__ captions,
                                                const float* __restrict__ emb,
                                                float* __restrict__ emb_all) {
    int i4 = blockIdx.x * 256 + threadIdx.x;      // over 1280 * (512/4)
    if (i4 >= Tt * Bsz * (Ee / 4)) return;
    int row = i4 >> 7, e4 = i4 & 127;
    int t = row / Bsz, b = row % Bsz;
    int cap = captions[b * Tt + t];
    float4 val = ((const float4*)(emb + (size_t)cap * Ee))[e4];
    ((float4*)(emb_all + (size_t)row * Ee))[e4] = val;
}

// Generic C[M,N] = A[M,K] @ B[N,K]^T epilogues.
// MODE 0: C = acc + bias (+bias2)
// MODE 1: C = sigmoid(acc+bias) * extra[m,n]
// MODE 3: row-remap for preds: m = t*64+b -> out row b*20+t
template<int BM, int BN, int BK, int TM, int TN, int MODE>
__global__ __launch_bounds__(256) void gemm_bt(const float* __restrict__ A, int lda,
                                               const float* __restrict__ Bm, int ldb,
                                               float* __restrict__ C, int ldc,
                                               int M, int N, int K,
                                               const float* __restrict__ bias,
                                               const float* __restrict__ bias2,
                                               const float* __restrict__ extra, int extra_ld) {
    constexpr int TX = BN / TN, TY = BM / TM;
    static_assert(TX * TY == 256, "256 threads");
    const int tid = threadIdx.x;
    const int tx = tid % TX, ty = tid / TX;
    const int m0 = blockIdx.y * BM, n0 = blockIdx.x * BN;

    __shared__ float As[BK][BM + 1];
    __shared__ float Bs[BK][BN + 1];

    float acc[TM][TN] = {};

    for (int k0 = 0; k0 < K; k0 += BK) {
        for (int idx = tid; idx < BM * BK; idx += 256) {
            int mm = idx / BK, kk = idx % BK;
            As[kk][mm] = A[(size_t)(m0 + mm) * lda + k0 + kk];
        }
        for (int idx = tid; idx < BN * BK; idx += 256) {
            int nn = idx / BK, kk = idx % BK;
            int gn = n0 + nn;
            Bs[kk][nn] = (gn < N) ? Bm[(size_t)gn * ldb + k0 + kk] : 0.f;
        }
        __syncthreads();
        #pragma unroll
        for (int kk = 0; kk < BK; ++kk) {
            float a[TM], bb[TN];
            #pragma unroll
            for (int i = 0; i < TM; ++i) a[i] = As[kk][ty * TM + i];
            #pragma unroll
            for (int j = 0; j < TN; ++j) bb[j] = Bs[kk][tx * TN + j];
            #pragma unroll
            for (int i = 0; i < TM; ++i)
                #pragma unroll
                for (int j = 0; j < TN; ++j)
                    acc[i][j] += a[i] * bb[j];
        }
        __syncthreads();
    }

    #pragma unroll
    for (int i = 0; i < TM; ++i) {
        int m = m0 + ty * TM + i;
        #pragma unroll
        for (int j = 0; j < TN; ++j) {
            int gn = n0 + tx * TN + j;
            if (gn >= N) continue;
            float v = acc[i][j] + bias[gn];
            if (bias2) v += bias2[gn];
            if (MODE == 0) {
                C[(size_t)m * ldc + gn] = v;
            } else if (MODE == 1) {
                float s = sigmoidf_(v);
                C[(size_t)m * ldc + gn] = s * extra[(size_t)m * extra_ld + gn];
            } else {  // MODE 3
                int t = m >> 6, b = m & 63;
                C[(size_t)(b * Tt + t) * ldc + gn] = v;
            }
        }
    }
}

// gates = A1@B1^T + A2@B2^T + D  (M=64 fixed; thin tile 64x16)
__global__ __launch_bounds__(256) void gemm_dual(const float* __restrict__ A1, int lda1,
                                                 const float* __restrict__ B1, int ldb1, int K1,
                                                 const float* __restrict__ A2, int lda2,
                                                 const float* __restrict__ B2, int ldb2, int K2,
                                                 const float* __restrict__ D, int ldD,
                                                 float* __restrict__ C, int ldc, int N) {
    constexpr int BM = 64, BN = 16, BK = 32, TM = 4;
    const int tid = threadIdx.x;
    const int tx = tid % 16, ty = tid / 16;
    const int n0 = blockIdx.x * BN;

    __shared__ float As[BK][BM + 1];
    __shared__ float Bs[BK][BN + 1];

    float acc[TM] = {};

    for (int pass = 0; pass < 2; ++pass) {
        const float* A = pass ? A2 : A1;
        const float* Bm = pass ? B2 : B1;
        int lda = pass ? lda2 : lda1;
        int ldb = pass ? ldb2 : ldb1;
        int K = pass ? K2 : K1;
        for (int k0 = 0; k0 < K; k0 += BK) {
            for (int idx = tid; idx < BM * BK; idx += 256) {
                int mm = idx / BK, kk = idx % BK;
                As[kk][mm] = A[(size_t)mm * lda + k0 + kk];
            }
            for (int idx = tid; idx < BN * BK; idx += 256) {
                int nn = idx / BK, kk = idx % BK;
                Bs[kk][nn] = Bm[(size_t)(n0 + nn) * ldb + k0 + kk];
            }
            __syncthreads();
            #pragma unroll
            for (int kk = 0; kk < BK; ++kk) {
                float bb = Bs[kk][tx];
                #pragma unroll
                for (int i = 0; i < TM; ++i) acc[i] += As[kk][ty * TM + i] * bb;
            }
            __syncthreads();
        }
    }

    #pragma unroll
    for (int i = 0; i < TM; ++i) {
        int m = ty * TM + i;
        int gn = n0 + tx;
        C[(size_t)m * ldc + gn] = acc[i] + D[(size_t)m * ldD + gn];
    }
}

// LSTM pointwise update; writes h, c in place and H_all slice for step t
__global__ __launch_bounds__(256) void k_lstm(const float* __restrict__ gates,
                                              float* __restrict__ h,
                                              float* __restrict__ c,
                                              float* __restrict__ Hall_t) {
    int idx = blockIdx.x * 256 + threadIdx.x;  // < 64*512
    if (idx >= Bsz * Hh) return;
    int b = idx >> 9, j = idx & 511;
    const float* g = gates + (size_t)b * H4;
    float i_ = sigmoidf_(g[j]);
    float f_ = sigmoidf_(g[j + 512]);
    float g_ = tanhf(g[j + 1024]);
    float o_ = sigmoidf_(g[j + 1536]);
    float cn = f_ * c[idx] + i_ * g_;
    float hn = o_ * tanhf(cn);
    c[idx] = cn;
    h[idx] = hn;
    Hall_t[idx] = hn;
}

extern "C" void kernel_launch(void* const* d_in, const int* in_sizes, int n_in,
                              void* d_out, int out_size, void* d_ws, size_t ws_size,
                              hipStream_t stream) {
    const float* img_feat  = (const float*)d_in[0];
    const int*   captions  = (const int*)d_in[1];
    const float* embedding = (const float*)d_in[2];
    const float* W_enc_att = (const float*)d_in[3];
    // d_in[4] b_enc_att, d_in[5] W_dec_att, d_in[6] b_dec_att, d_in[8] b_full: softmax-invariant, unused
    const float* W_full    = (const float*)d_in[7];
    const float* W_beta    = (const float*)d_in[9];
    const float* b_beta    = (const float*)d_in[10];
    const float* W_ih      = (const float*)d_in[11];
    const float* b_ih      = (const float*)d_in[12];
    const float* W_hh      = (const float*)d_in[13];
    const float* b_hh      = (const float*)d_in[14];
    const float* W_init_h  = (const float*)d_in[15];
    const float* b_init_h  = (const float*)d_in[16];
    const float* W_init_c  = (const float*)d_in[17];
    const float* b_init_c  = (const float*)d_in[18];
    const float* W_out     = (const float*)d_in[19];
    const float* b_out     = (const float*)d_in[20];

    float* preds_out  = (float*)d_out;                       // [B,T,V]
    float* alphas_out = (float*)d_out + (size_t)Bsz * Tt * Vv; // [B,T,P]

    // workspace layout (floats)
    float* ws = (float*)d_ws;
    float* v_enc    = ws;                 // 2048
    float* context  = v_enc + ENC;        // 64*2048
    float* avg      = context + Bsz*ENC;  // 64*2048
    float* h        = avg + Bsz*ENC;      // 64*512
    float* c        = h + Bsz*Hh;         // 64*512
    float* emb_all  = c + Bsz*Hh;         // 1280*512
    float* emb_part = emb_all + Tt*Bsz*Ee;   // 1280*2048
    float* gc       = emb_part + (size_t)Tt*Bsz*H4; // 64*2048
    float* gates    = gc + Bsz*ENC;       // 64*2048
    float* H_all    = gates + Bsz*H4;     // 1280*512

    // 1) v_enc
    k_venc<<<ENC / 256, 256, 0, stream>>>(W_full, W_enc_att, v_enc);

    // 2) attention (alpha, alphas out, context, avg) — timestep-invariant
    k_attn<<<Bsz, 256, 0, stream>>>(img_feat, v_enc, context, avg, alphas_out);

    // 3) h0, c0 : [64,512] = avg[64,2048] @ W_init^T
    gemm_bt<64,16,32,4,1,0><<<dim3(Hh/16, 1), 256, 0, stream>>>(
        avg, ENC, W_init_h, ENC, h, Hh, Bsz, Hh, ENC, b_init_h, nullptr, nullptr, 0);
    gemm_bt<64,16,32,4,1,0><<<dim3(Hh/16, 1), 256, 0, stream>>>(
        avg, ENC, W_init_c, ENC, c, Hh, Bsz, Hh, ENC, b_init_c, nullptr, nullptr, 0);

    // 4) embedding gather + emb_part = E_all @ W_ih[:, :E]^T + (b_ih + b_hh)
    k_gather<<<(Tt * Bsz * (Ee / 4) + 255) / 256, 256, 0, stream>>>(captions, embedding, emb_all);
    gemm_bt<64,64,32,4,4,0><<<dim3(H4/64, (Tt*Bsz)/64), 256, 0, stream>>>(
        emb_all, Ee, W_ih, Ee + ENC, emb_part, H4, Tt*Bsz, H4, Ee, b_ih, b_hh, nullptr, 0);

    // 5) sequential LSTM loop
    for (int t = 0; t < Tt; ++t) {
        // gc = sigmoid(h @ W_beta^T + b_beta) * context   [64, 2048], K=512
        gemm_bt<64,16,32,4,1,1><<<dim3(ENC/16, 1), 256, 0, stream>>>(
            h, Hh, W_beta, Hh, gc, ENC, Bsz, ENC, Hh, b_beta, nullptr, context, ENC);
        // gates = emb_part[t] + gc @ W_ih[:,E:]^T + h @ W_hh^T   [64, 2048]
        gemm_dual<<<dim3(H4/16, 1), 256, 0, stream>>>(
            gc, ENC, W_ih + Ee, Ee + ENC, ENC,
            h, Hh, W_hh, Hh, Hh,
            emb_part + (size_t)t * Bsz * H4, H4,
            gates, H4, H4);
        // pointwise LSTM
        k_lstm<<<(Bsz * Hh) / 256, 256, 0, stream>>>(gates, h, c, H_all + (size_t)t * Bsz * Hh);
    }

    // 6) preds = H_all @ W_out^T + b_out, rows remapped (t*64+b) -> (b*20+t)
    gemm_bt<64,64,32,4,4,3><<<dim3((Vv + 63) / 64, (Tt*Bsz)/64), 256, 0, stream>>>(
        H_all, Hh, W_out, Hh, preds_out, Vv, Tt*Bsz, Vv, Hh, b_out, nullptr, nullptr, 0);
}

// Round 2
// 2187.136 us; speedup vs baseline: 4.0167x; 4.0167x over previous
//
#include <hip/hip_runtime.h>
#include <hip/hip_bf16.h>
#include <math.h>

#define Bsz 64
#define Pp  196
#define ENC 2048
#define Ee  512
#define Hh  512
#define Vv  10000
#define Tt  20
#define H4  2048

__device__ __forceinline__ float sigmoidf_(float x) { return 1.0f / (1.0f + expf(-x)); }

// ---------------- v_enc[e] = sum_a W_full[a] * W_enc[a][e] ----------------
// 32 blocks; block covers 64 e's; 4 wave-groups split the a-range; LDS reduce.
__global__ __launch_bounds__(256) void k_venc(const float* __restrict__ W_full,
                                              const float* __restrict__ W_enc,
                                              float* __restrict__ v_enc) {
    int lane = threadIdx.x & 63, ag = threadIdx.x >> 6;
    int e = blockIdx.x * 64 + lane;
    float s = 0.f;
    #pragma unroll 8
    for (int a = ag * 128; a < ag * 128 + 128; ++a)
        s += W_full[a] * W_enc[(size_t)a * ENC + e];
    __shared__ float red[4][64];
    red[ag][lane] = s;
    __syncthreads();
    if (threadIdx.x < 64)
        v_enc[e] = red[0][lane] + red[1][lane] + red[2][lane] + red[3][lane];
}

// ---------------- scores: sc[b][p] = dot(img[b][p], v_enc) ----------------
// grid (49, 64); one wave per p.
__global__ __launch_bounds__(256) void k_scores(const float* __restrict__ img,
                                                const float* __restrict__ v_enc,
                                                float* __restrict__ sc) {
    int b = blockIdx.y;
    int wave = threadIdx.x >> 6, lane = threadIdx.x & 63;
    int p = blockIdx.x * 4 + wave;
    __shared__ float4 sv[ENC / 4];
    const float4* ve4 = (const float4*)v_enc;
    sv[threadIdx.x] = ve4[threadIdx.x];
    sv[threadIdx.x + 256] = ve4[threadIdx.x + 256];
    __syncthreads();
    const float4* row = (const float4*)(img + ((size_t)b * Pp + p) * ENC);
    float s = 0.f;
    #pragma unroll
    for (int it = 0; it < 8; ++it) {
        int idx = it * 64 + lane;
        float4 v = row[idx];
        float4 w = sv[idx];
        s += v.x * w.x + v.y * w.y + v.z * w.z + v.w * w.w;
    }
    #pragma unroll
    for (int off = 32; off > 0; off >>= 1) s += __shfl_down(s, off);
    if (lane == 0) sc[b * Pp + p] = s;
}

// ---------------- softmax over p; writes alpha + broadcast alphas_out ----------------
__global__ __launch_bounds__(256) void k_softmax(const float* __restrict__ sc,
                                                 float* __restrict__ alpha,
                                                 float* __restrict__ alphas_out) {
    int b = blockIdx.x, tid = threadIdx.x;
    __shared__ float red[256];
    __shared__ float sa[Pp];
    float v = (tid < Pp) ? sc[b * Pp + tid] : -INFINITY;
    red[tid] = v; __syncthreads();
    for (int off = 128; off > 0; off >>= 1) {
        if (tid < off) red[tid] = fmaxf(red[tid], red[tid + off]);
        __syncthreads();
    }
    float mx = red[0]; __syncthreads();
    float ex = (tid < Pp) ? expf(v - mx) : 0.f;
    red[tid] = ex; __syncthreads();
    for (int off = 128; off > 0; off >>= 1) {
        if (tid < off) red[tid] += red[tid + off];
        __syncthreads();
    }
    float inv = 1.f / red[0];
    if (tid < Pp) { sa[tid] = ex * inv; alpha[b * Pp + tid] = ex * inv; }
    __syncthreads();
    for (int i = tid; i < Tt * Pp; i += 256)
        alphas_out[(size_t)b * Tt * Pp + i] = sa[i % Pp];
}

// ---------------- context + avg (float2 columns) ----------------
// grid (4, 64): block covers 512 floats (256 float2) of e.
__global__ __launch_bounds__(256) void k_ctx(const float* __restrict__ img,
                                             const float* __restrict__ alpha,
                                             float* __restrict__ context,
                                             float* __restrict__ avg) {
    int b = blockIdx.y;
    int e2 = blockIdx.x * 256 + threadIdx.x;   // float2 index, < 1024
    __shared__ float sa[Pp];
    if (threadIdx.x < Pp) sa[threadIdx.x] = alpha[b * Pp + threadIdx.x];
    __syncthreads();
    const float2* ib2 = (const float2*)(img + (size_t)b * Pp * ENC);
    float cx = 0.f, cy = 0.f, ax = 0.f, ay = 0.f;
    for (int p = 0; p < Pp; p += 4) {
        #pragma unroll
        for (int q = 0; q < 4; ++q) {
            float ap = sa[p + q];
            float2 v = ib2[(size_t)(p + q) * (ENC / 2) + e2];
            cx += ap * v.x; cy += ap * v.y;
            ax += v.x;      ay += v.y;
        }
    }
    float2* c2 = (float2*)(context + (size_t)b * ENC);
    float2* a2 = (float2*)(avg + (size_t)b * ENC);
    c2[e2] = make_float2(cx, cy);
    a2[e2] = make_float2(ax * (1.f / 196.f), ay * (1.f / 196.f));
}

// emb_all[(t*B+b)*E + e] = embedding[captions[b*T+t]*E + e]
__global__ __launch_bounds__(256) void k_gather(const int* __restrict__ captions,
                                                const float* __restrict__ emb,
                                                float* __restrict__ emb_all) {
    int i4 = blockIdx.x * 256 + threadIdx.x;
    if (i4 >= Tt * Bsz * (Ee / 4)) return;
    int row = i4 >> 7, e4 = i4 & 127;
    int t = row / Bsz, b = row % Bsz;
    int cap = captions[b * Tt + t];
    float4 val = ((const float4*)(emb + (size_t)cap * Ee))[e4];
    ((float4*)(emb_all + (size_t)row * Ee))[e4] = val;
}

// ---------------- M=64 GEMM family: BM=64, BN=16, BK=64, TM=4 ----------------
// MODE 0 (INIT): C[64,1024]=avg@[Winit_h|Winit_c]^T + bias; B selected by n0
// MODE 1 (GC):   C = sigmoid(acc + bias1) * extra
// MODE 2 (GATES): z-split over K; atomicAdd into C (pre-filled with emb part)
template<int MODE>
__global__ __launch_bounds__(256) void gemm64(
    const float* __restrict__ A1, int lda1, const float* __restrict__ B1, int ldb1, int K1,
    const float* __restrict__ A2, int lda2, const float* __restrict__ B2, int ldb2,
    float* __restrict__ C, int ldc,
    const float* __restrict__ bias1, const float* __restrict__ bias2,
    const float* __restrict__ extra, int extra_ld) {
    const int tid = threadIdx.x;
    const int tx = tid & 15, ty = tid >> 4;          // tx: n (16), ty: m-group (16)
    const int n0 = blockIdx.x * 16;

    __shared__ float As[64][68];   // [kk][m], row stride 68 (16B-aligned rows)
    __shared__ float Bs[64][20];   // [kk][n]

    // pair table
    const float* Ap[2]; int Alda[2]; const float* Bp[2]; int Bldb[2];
    int Koff[2]; int nck[2]; int npair;
    if (MODE == 2) {
        if (blockIdx.y == 0) {
            Ap[0] = A1; Alda[0] = lda1; Bp[0] = B1 + (size_t)n0 * ldb1; Bldb[0] = ldb1;
            Koff[0] = 0; nck[0] = 20; npair = 1;
        } else {
            Ap[0] = A1; Alda[0] = lda1; Bp[0] = B1 + (size_t)n0 * ldb1; Bldb[0] = ldb1;
            Koff[0] = 1280; nck[0] = 12;
            Ap[1] = A2; Alda[1] = lda2; Bp[1] = B2 + (size_t)n0 * ldb2; Bldb[1] = ldb2;
            Koff[1] = 0; nck[1] = 8; npair = 2;
        }
    } else if (MODE == 0) {
        const float* Bi = (n0 < 512) ? B1 : B2;
        int nn0 = (n0 < 512) ? n0 : n0 - 512;
        Ap[0] = A1; Alda[0] = lda1; Bp[0] = Bi + (size_t)nn0 * ldb1; Bldb[0] = ldb1;
        Koff[0] = 0; nck[0] = K1 / 64; npair = 1;
    } else {
        Ap[0] = A1; Alda[0] = lda1; Bp[0] = B1 + (size_t)n0 * ldb1; Bldb[0] = ldb1;
        Koff[0] = 0; nck[0] = K1 / 64; npair = 1;
    }
    int ncتotal;
    int nctotal = nck[0] + ((MODE == 2 && npair == 2) ? nck[1] : 0);
    (void)ncتotal;

    float4 pa[4]; float4 pb;
    // per-thread staging coordinates
    const int sm[4] = { (0 * 256 + tid) >> 4, (1 * 256 + tid) >> 4,
                        (2 * 256 + tid) >> 4, (3 * 256 + tid) >> 4 };
    const int scc = tid & 15;                 // float4 col within 64-k chunk (A)
    const int bn = tid >> 4, bc = tid & 15;   // B: row, float4 col

    auto load_chunk = [&](int c) {
        int pi = (c < nck[0]) ? 0 : 1;
        int lc = (c < nck[0]) ? c : c - nck[0];
        int k0 = Koff[pi] + lc * 64;
        const float* A = Ap[pi]; int la = Alda[pi];
        #pragma unroll
        for (int i = 0; i < 4; ++i)
            pa[i] = *(const float4*)(A + (size_t)sm[i] * la + k0 + 4 * scc);
        pb = *(const float4*)(Bp[pi] + (size_t)bn * Bldb[pi] + k0 + 4 * bc);
    };

    float acc[4] = {};
    load_chunk(0);
    for (int c = 0; c < nctotal; ++c) {
        __syncthreads();
        #pragma unroll
        for (int i = 0; i < 4; ++i) {
            As[4 * scc + 0][sm[i]] = pa[i].x;
            As[4 * scc + 1][sm[i]] = pa[i].y;
            As[4 * scc + 2][sm[i]] = pa[i].z;
            As[4 * scc + 3][sm[i]] = pa[i].w;
        }
        Bs[4 * bc + 0][bn] = pb.x;
        Bs[4 * bc + 1][bn] = pb.y;
        Bs[4 * bc + 2][bn] = pb.z;
        Bs[4 * bc + 3][bn] = pb.w;
        __syncthreads();
        if (c + 1 < nctotal) load_chunk(c + 1);
        #pragma unroll 8
        for (int kk = 0; kk < 64; ++kk) {
            float4 a = *(const float4*)&As[kk][ty * 4];
            float bb = Bs[kk][tx];
            acc[0] += a.x * bb; acc[1] += a.y * bb;
            acc[2] += a.z * bb; acc[3] += a.w * bb;
        }
    }

    int gn = n0 + tx;
    #pragma unroll
    for (int i = 0; i < 4; ++i) {
        int m = ty * 4 + i;
        if (MODE == 0) {
            float bsel = (n0 < 512) ? bias1[gn] : bias2[gn - 512];
            C[(size_t)m * ldc + gn] = acc[i] + bsel;
        } else if (MODE == 1) {
            float s = sigmoidf_(acc[i] + bias1[gn]);
            C[(size_t)m * ldc + gn] = s * extra[(size_t)m * extra_ld + gn];
        } else {
            atomicAdd(&C[(size_t)m * ldc + gn], acc[i]);
        }
    }
}

// ---------------- big GEMM: BM=128, BN=64, BK=32, TM=8, TN=4 ----------------
// MODE 0: C = acc + bias + bias2   (emb_part)
// MODE 1: preds row-remap (t*64+b -> b*20+t) + bias, guard n<N
template<int MODE>
__global__ __launch_bounds__(256) void gemm_big(const float* __restrict__ A, int lda,
                                                const float* __restrict__ Bm, int ldb,
                                                float* __restrict__ C, int ldc,
                                                int N, int K,
                                                const float* __restrict__ bias,
                                                const float* __restrict__ bias2) {
    const int tid = threadIdx.x;
    const int tx = tid & 15, ty = tid >> 4;
    const int m0 = blockIdx.y * 128, n0 = blockIdx.x * 64;

    __shared__ float As[32][132];
    __shared__ float Bs[32][68];

    float4 pa[4]; float4 pb[2];
    const int am[4] = { (0 * 256 + tid) >> 3, (1 * 256 + tid) >> 3,
                        (2 * 256 + tid) >> 3, (3 * 256 + tid) >> 3 };
    const int ac = tid & 7;
    const int bnr[2] = { (0 * 256 + tid) >> 3, (1 * 256 + tid) >> 3 };
    const int bc = tid & 7;

    const int nchunk = K / 32;
    auto load_chunk = [&](int c) {
        int k0 = c * 32;
        #pragma unroll
        for (int i = 0; i < 4; ++i)
            pa[i] = *(const float4*)(A + (size_t)(m0 + am[i]) * lda + k0 + 4 * ac);
        #pragma unroll
        for (int i = 0; i < 2; ++i) {
            int gn = n0 + bnr[i];
            if (MODE == 1 && gn >= N) pb[i] = make_float4(0.f, 0.f, 0.f, 0.f);
            else pb[i] = *(const float4*)(Bm + (size_t)gn * ldb + k0 + 4 * bc);
        }
    };

    float acc[8][4] = {};
    load_chunk(0);
    for (int c = 0; c < nchunk; ++c) {
        __syncthreads();
        #pragma unroll
        for (int i = 0; i < 4; ++i) {
            As[4 * ac + 0][am[i]] = pa[i].x;
            As[4 * ac + 1][am[i]] = pa[i].y;
            As[4 * ac + 2][am[i]] = pa[i].z;
            As[4 * ac + 3][am[i]] = pa[i].w;
        }
        #pragma unroll
        for (int i = 0; i < 2; ++i) {
            Bs[4 * bc + 0][bnr[i]] = pb[i].x;
            Bs[4 * bc + 1][bnr[i]] = pb[i].y;
            Bs[4 * bc + 2][bnr[i]] = pb[i].z;
            Bs[4 * bc + 3][bnr[i]] = pb[i].w;
        }
        __syncthreads();
        if (c + 1 < nchunk) load_chunk(c + 1);
        #pragma unroll 4
        for (int kk = 0; kk < 32; ++kk) {
            float4 a0 = *(const float4*)&As[kk][ty * 8];
            float4 a1 = *(const float4*)&As[kk][ty * 8 + 4];
            float4 b0 = *(const float4*)&Bs[kk][tx * 4];
            float av[8] = { a0.x, a0.y, a0.z, a0.w, a1.x, a1.y, a1.z, a1.w };
            float bv[4] = { b0.x, b0.y, b0.z, b0.w };
            #pragma unroll
            for (int i = 0; i < 8; ++i)
                #pragma unroll
                for (int j = 0; j < 4; ++j)
                    acc[i][j] += av[i] * bv[j];
        }
    }

    #pragma unroll
    for (int i = 0; i < 8; ++i) {
        int m = m0 + ty * 8 + i;
        #pragma unroll
        for (int j = 0; j < 4; ++j) {
            int gn = n0 + tx * 4 + j;
            if (MODE == 1 && gn >= N) continue;
            float v = acc[i][j] + bias[gn];
            if (MODE == 0) {
                v += bias2[gn];
                C[(size_t)m * ldc + gn] = v;
            } else {
                int t = m >> 6, b = m & 63;
                C[(size_t)(b * Tt + t) * ldc + gn] = v;
            }
        }
    }
}

// ---------------- LSTM pointwise ----------------
__global__ __launch_bounds__(256) void k_lstm(const float* __restrict__ gates,
                                              float* __restrict__ hc,
                                              float* __restrict__ Hall_t) {
    int idx = blockIdx.x * 256 + threadIdx.x;  // < 64*512
    int b = idx >> 9, j = idx & 511;
    const float* g = gates + (size_t)b * H4;
    float i_ = sigmoidf_(g[j]);
    float f_ = sigmoidf_(g[j + 512]);
    float g_ = tanhf(g[j + 1024]);
    float o_ = sigmoidf_(g[j + 1536]);
    float* hrow = hc + (size_t)b * 1024;
    float cn = f_ * hrow[512 + j] + i_ * g_;
    float hn = o_ * tanhf(cn);
    hrow[512 + j] = cn;
    hrow[j] = hn;
    Hall_t[(size_t)b * Hh + j] = hn;
}

extern "C" void kernel_launch(void* const* d_in, const int* in_sizes, int n_in,
                              void* d_out, int out_size, void* d_ws, size_t ws_size,
                              hipStream_t stream) {
    const float* img_feat  = (const float*)d_in[0];
    const int*   captions  = (const int*)d_in[1];
    const float* embedding = (const float*)d_in[2];
    const float* W_enc_att = (const float*)d_in[3];
    const float* W_full    = (const float*)d_in[7];
    const float* W_beta    = (const float*)d_in[9];
    const float* b_beta    = (const float*)d_in[10];
    const float* W_ih      = (const float*)d_in[11];
    const float* b_ih      = (const float*)d_in[12];
    const float* W_hh      = (const float*)d_in[13];
    const float* b_hh      = (const float*)d_in[14];
    const float* W_init_h  = (const float*)d_in[15];
    const float* b_init_h  = (const float*)d_in[16];
    const float* W_init_c  = (const float*)d_in[17];
    const float* b_init_c  = (const float*)d_in[18];
    const float* W_out     = (const float*)d_in[19];
    const float* b_out     = (const float*)d_in[20];

    float* preds_out  = (float*)d_out;
    float* alphas_out = (float*)d_out + (size_t)Bsz * Tt * Vv;

    float* ws = (float*)d_ws;
    float* v_enc   = ws;                       // 2048
    float* sc      = v_enc + ENC;              // 64*196
    float* alpha   = sc + Bsz * Pp;            // 64*196
    float* context = alpha + Bsz * Pp;         // 64*2048
    float* avg     = context + Bsz * ENC;      // 64*2048
    float* hc      = avg + Bsz * ENC;          // 64*1024 (h | c)
    float* emb_all = hc + Bsz * 1024;          // 1280*512
    float* emb_part = emb_all + Tt * Bsz * Ee; // 1280*2048 (becomes gates)
    float* H_all   = emb_part + (size_t)Tt * Bsz * H4; // 1280*512

    // attention (timestep-invariant)
    k_venc<<<32, 256, 0, stream>>>(W_full, W_enc_att, v_enc);
    k_scores<<<dim3(49, 64), 256, 0, stream>>>(img_feat, v_enc, sc);
    k_softmax<<<64, 256, 0, stream>>>(sc, alpha, alphas_out);
    k_ctx<<<dim3(4, 64), 256, 0, stream>>>(img_feat, alpha, context, avg);

    // hc init: [64,1024] = avg @ [Winit_h | Winit_c]^T + bias
    gemm64<0><<<64, 256, 0, stream>>>(
        avg, ENC, W_init_h, ENC, ENC,
        nullptr, 0, W_init_c, ENC,
        hc, 1024, b_init_h, b_init_c, nullptr, 0);

    // embedding part of gates for all steps
    k_gather<<<(Tt * Bsz * (Ee / 4) + 255) / 256, 256, 0, stream>>>(captions, embedding, emb_all);
    gemm_big<0><<<dim3(H4 / 64, (Tt * Bsz) / 128), 256, 0, stream>>>(
        emb_all, Ee, W_ih, Ee + ENC, emb_part, H4, H4, Ee, b_ih, b_hh);

    float* gc = context + 0;  // placeholder; real gc buffer below
    // reuse sc/alpha region? no — allocate gc after H_all
    gc = H_all + (size_t)Tt * Bsz * Hh;        // 64*2048

    for (int t = 0; t < Tt; ++t) {
        float* gates_t = emb_part + (size_t)t * Bsz * H4;
        // gc = sigmoid(h @ Wb^T + b_beta) * context
        gemm64<1><<<dim3(128, 1), 256, 0, stream>>>(
            hc, 1024, W_beta, Hh, Hh,
            nullptr, 0, nullptr, 0,
            gc, ENC, b_beta, nullptr, context, ENC);
        // gates += gc @ W_ih[:,E:]^T + h @ W_hh^T   (K-split z=2, atomic)
        gemm64<2><<<dim3(128, 2), 256, 0, stream>>>(
            gc, ENC, W_ih + Ee, Ee + ENC, ENC,
            hc, 1024, W_hh, Hh,
            gates_t, H4, nullptr, nullptr, nullptr, 0);
        // LSTM pointwise
        k_lstm<<<128, 256, 0, stream>>>(gates_t, hc, H_all + (size_t)t * Bsz * Hh);
    }

    // preds = H_all @ W_out^T + b_out (row remap)
    gemm_big<1><<<dim3((Vv + 63) / 64, (Tt * Bsz) / 128), 256, 0, stream>>>(
        H_all, Hh, W_out, Hh, preds_out, Vv, Vv, Hh, b_out, nullptr);
}